// Round 2
// baseline (99.248 us; speedup 1.0000x reference)
//
#include <hip/hip_runtime.h>

typedef __attribute__((ext_vector_type(8))) short bf16x8;
typedef __attribute__((ext_vector_type(4))) float f32x4;
typedef __attribute__((ext_vector_type(4))) float f4v;

#define NB 16
#define NC 128
#define NN 16384

// RNE pack of two fp32 -> one u32 holding two bf16 (lo | hi<<16)
__device__ __forceinline__ unsigned int f2bf_pack(float lo, float hi) {
  unsigned int ulo = __float_as_uint(lo);
  unsigned int uhi = __float_as_uint(hi);
  ulo = (ulo + 0x7FFFu + ((ulo >> 16) & 1u)) >> 16;
  uhi = (uhi + 0x7FFFu + ((uhi >> 16) & 1u)) & 0xFFFF0000u;
  return ulo | uhi;
}

// ---------------- Kernel A: partial Gram per (batch, K-chunk) ----------------
// gram_partial = Xc @ Xc^T  (bf16 MFMA, fp32 accum), Xc = x[b, :, ch*kc : (ch+1)*kc]
__global__ __launch_bounds__(256, 2)
void nlm_gram_kernel(const float* __restrict__ x, float* __restrict__ partials,
                     int chunks, int ksteps) {
  __shared__ __align__(16) char lds[2 * 128 * 64 * 2];  // 2 x [128 rows][64 k] bf16, swizzled
  const int t = threadIdx.x;
  const int b  = blockIdx.x / chunks;
  const int ch = blockIdx.x % chunks;
  const int lane = t & 63, wv = t >> 6, l15 = lane & 15, q = lane >> 4;
  const int kc = ksteps * 64;

  const float* xb = x + (size_t)b * NC * NN + (size_t)ch * kc;

  f32x4 acc[2][8];
#pragma unroll
  for (int i = 0; i < 2; ++i)
#pragma unroll
    for (int j = 0; j < 8; ++j) acc[i][j] = (f32x4){0.f, 0.f, 0.f, 0.f};

  // staging tasks: 128 rows x 8 segs(8 floats) = 1024 tasks / 256 thr = 4 each
  int srow[4], sseg[4];
#pragma unroll
  for (int i = 0; i < 4; ++i) { int id = t + 256 * i; srow[i] = id >> 3; sseg[i] = id & 7; }

  f4v pf[4][2];

  // prologue: stage k-step 0 into buffer 0
#pragma unroll
  for (int i = 0; i < 4; ++i) {
    const float* src = xb + (size_t)srow[i] * NN + sseg[i] * 8;
    pf[i][0] = *(const f4v*)src;
    pf[i][1] = *(const f4v*)(src + 4);
  }
#pragma unroll
  for (int i = 0; i < 4; ++i) {
    uint4 pk;
    pk.x = f2bf_pack(pf[i][0][0], pf[i][0][1]);
    pk.y = f2bf_pack(pf[i][0][2], pf[i][0][3]);
    pk.z = f2bf_pack(pf[i][1][0], pf[i][1][1]);
    pk.w = f2bf_pack(pf[i][1][2], pf[i][1][3]);
    int byte = (srow[i] * 128 + sseg[i] * 16) ^ ((srow[i] & 7) << 4);
    *(uint4*)(lds + byte) = pk;
  }
  __syncthreads();

  for (int ks = 0; ks < ksteps; ++ks) {
    char* cur = lds + (ks & 1) * 16384;
    char* nxt = lds + ((ks + 1) & 1) * 16384;
    const bool more = (ks + 1) < ksteps;

    if (more) {  // issue next-tile global loads early; they overlap the MFMAs below
#pragma unroll
      for (int i = 0; i < 4; ++i) {
        const float* src = xb + (size_t)srow[i] * NN + (ks + 1) * 64 + sseg[i] * 8;
        pf[i][0] = *(const f4v*)src;
        pf[i][1] = *(const f4v*)(src + 4);
      }
    }

#pragma unroll
    for (int kh = 0; kh < 2; ++kh) {
      const int kbyte = kh * 64 + q * 16;
      int ra = wv * 32 + l15;
      bf16x8 a0 = *(const bf16x8*)(cur + ((ra * 128 + kbyte) ^ ((ra & 7) << 4)));
      int rb = wv * 32 + 16 + l15;
      bf16x8 a1 = *(const bf16x8*)(cur + ((rb * 128 + kbyte) ^ ((rb & 7) << 4)));
#pragma unroll
      for (int ct = 0; ct < 8; ++ct) {
        int rc = ct * 16 + l15;
        bf16x8 bb = *(const bf16x8*)(cur + ((rc * 128 + kbyte) ^ ((rc & 7) << 4)));
        acc[0][ct] = __builtin_amdgcn_mfma_f32_16x16x32_bf16(a0, bb, acc[0][ct], 0, 0, 0);
        acc[1][ct] = __builtin_amdgcn_mfma_f32_16x16x32_bf16(a1, bb, acc[1][ct], 0, 0, 0);
      }
    }

    if (more) {  // convert + write next tile (write-after-read safe: 2 buffers, barrier below)
#pragma unroll
      for (int i = 0; i < 4; ++i) {
        uint4 pk;
        pk.x = f2bf_pack(pf[i][0][0], pf[i][0][1]);
        pk.y = f2bf_pack(pf[i][0][2], pf[i][0][3]);
        pk.z = f2bf_pack(pf[i][1][0], pf[i][1][1]);
        pk.w = f2bf_pack(pf[i][1][2], pf[i][1][3]);
        int byte = (srow[i] * 128 + sseg[i] * 16) ^ ((srow[i] & 7) << 4);
        *(uint4*)(nxt + byte) = pk;
      }
    }
    __syncthreads();
  }

  // C/D layout (verified m89): col = lane&15, row = (lane>>4)*4 + reg
  float* part = partials + (size_t)blockIdx.x * (NC * NC);
#pragma unroll
  for (int rt = 0; rt < 2; ++rt)
#pragma unroll
    for (int ct = 0; ct < 8; ++ct)
#pragma unroll
      for (int r = 0; r < 4; ++r) {
        int i = wv * 32 + rt * 16 + q * 4 + r;
        int j = ct * 16 + l15;
        part[i * 128 + j] = acc[rt][ct][r];
      }
}

// ---------------- Kernel R: reduce partial Grams (full-grid, vectorized) ----------------
__global__ __launch_bounds__(256)
void nlm_reduce_kernel(const float* __restrict__ partials, float* __restrict__ gram,
                       int chunks) {
  const int b = blockIdx.x >> 4;
  const int seg = blockIdx.x & 15;
  const int e0 = seg * 1024 + threadIdx.x * 4;
  const float* pb = partials + (size_t)b * chunks * (NC * NC) + e0;
  f4v s = (f4v){0.f, 0.f, 0.f, 0.f};
  for (int chn = 0; chn < chunks; ++chn)
    s += *(const f4v*)(pb + (size_t)chn * (NC * NC));
  s *= (1.0f / 16384.0f);
  *(f4v*)(gram + (size_t)b * (NC * NC) + e0) = s;
}

// ---------------- Kernel B2: M = w @ gram, emit bf16 ----------------
__global__ __launch_bounds__(256)
void nlm_wgram_kernel(const float* __restrict__ gram, const float* __restrict__ w,
                      unsigned short* __restrict__ Mbf) {
  __shared__ __align__(16) float glds[128 * 32];
  const int t = threadIdx.x;
  const int b = blockIdx.x >> 2;
  const int d0 = (blockIdx.x & 3) * 32;
  const float* gb = gram + (size_t)b * NC * NC;

#pragma unroll
  for (int i = 0; i < 16; ++i) {
    int idx = t + 256 * i;
    int c = idx >> 5, dd = idx & 31;
    glds[c * 32 + dd] = gb[c * 128 + d0 + dd];
  }
  __syncthreads();

  const int o0  = (t >> 3) * 4;   // 32 o-quads
  const int dd0 = (t & 7) * 4;    // 8 d-quads
  float a[4][4];
#pragma unroll
  for (int r = 0; r < 4; ++r)
#pragma unroll
    for (int j = 0; j < 4; ++j) a[r][j] = 0.f;

  for (int cb = 0; cb < 32; ++cb) {
    int c0 = cb * 4;
    f4v wr[4], gv[4];
#pragma unroll
    for (int r = 0; r < 4; ++r) wr[r] = *(const f4v*)(w + (o0 + r) * 128 + c0);
#pragma unroll
    for (int ii = 0; ii < 4; ++ii) gv[ii] = *(const f4v*)(glds + (c0 + ii) * 32 + dd0);
#pragma unroll
    for (int r = 0; r < 4; ++r)
#pragma unroll
      for (int ii = 0; ii < 4; ++ii)
#pragma unroll
        for (int j = 0; j < 4; ++j)
          a[r][j] = fmaf(wr[r][ii], gv[ii][j], a[r][j]);
  }

  unsigned short* mb = Mbf + (size_t)b * NC * NC;
#pragma unroll
  for (int r = 0; r < 4; ++r) {
    uint2 pk;
    pk.x = f2bf_pack(a[r][0], a[r][1]);
    pk.y = f2bf_pack(a[r][2], a[r][3]);
    *(uint2*)(mb + (o0 + r) * 128 + d0 + dd0) = pk;
  }
}

// ---------------- Kernel C: out = M @ X  (128 x 128 output tile per block) ----------------
__global__ __launch_bounds__(256, 2)
void nlm_out_kernel(const float* __restrict__ x, const unsigned short* __restrict__ Mbf,
                    float* __restrict__ out) {
  __shared__ __align__(16) char lds[128 * 128 * 2];  // X^T tile: [n=128][c=128] bf16, swizzled
  const int t = threadIdx.x;
  const int b = blockIdx.x >> 7;
  const int n0 = (blockIdx.x & 127) * 128;
  const int lane = t & 63, wv = t >> 6, l15 = lane & 15, q = lane >> 4;

  // A-operand (M) fragments straight from global into registers; L2-resident.
  bf16x8 afr[2][4];
  const unsigned short* mb = Mbf + (size_t)b * NC * NC;
#pragma unroll
  for (int rt = 0; rt < 2; ++rt)
#pragma unroll
    for (int ks = 0; ks < 4; ++ks) {
      int o = wv * 32 + rt * 16 + l15;
      afr[rt][ks] = *(const bf16x8*)(mb + o * 128 + ks * 32 + q * 8);
    }

  // stage X[b, :, n0:n0+128] transposed into LDS (8c x 4n register transpose per task)
  const float* xb = x + (size_t)b * NC * NN + n0;
#pragma unroll
  for (int i = 0; i < 2; ++i) {
    int id = t + 256 * i;
    int nb = id & 31, cb = id >> 5;  // cb in 0..15 (8 c-rows each)
    const float* src = xb + (size_t)(cb * 8) * NN + nb * 4;
    f4v v[8];
#pragma unroll
    for (int r = 0; r < 8; ++r) v[r] = *(const f4v*)(src + (size_t)r * NN);
#pragma unroll
    for (int j = 0; j < 4; ++j) {
      int n = nb * 4 + j;
      uint4 pk;
      pk.x = f2bf_pack(v[0][j], v[1][j]);
      pk.y = f2bf_pack(v[2][j], v[3][j]);
      pk.z = f2bf_pack(v[4][j], v[5][j]);
      pk.w = f2bf_pack(v[6][j], v[7][j]);
      int byte = (n * 256 + cb * 16) ^ ((((n & 7) ^ ((n >> 3) & 7))) << 4);
      *(uint4*)(lds + byte) = pk;
    }
  }
  __syncthreads();

  f32x4 acc[2][8];
#pragma unroll
  for (int i = 0; i < 2; ++i)
#pragma unroll
    for (int j = 0; j < 8; ++j) acc[i][j] = (f32x4){0.f, 0.f, 0.f, 0.f};

#pragma unroll
  for (int ks = 0; ks < 4; ++ks) {
#pragma unroll
    for (int ct = 0; ct < 8; ++ct) {
      int n = ct * 16 + l15;
      int byte = (n * 256 + ks * 64 + q * 16) ^ ((((n & 7) ^ ((n >> 3) & 7))) << 4);
      bf16x8 bfr = *(const bf16x8*)(lds + byte);
      acc[0][ct] = __builtin_amdgcn_mfma_f32_16x16x32_bf16(afr[0][ks], bfr, acc[0][ct], 0, 0, 0);
      acc[1][ct] = __builtin_amdgcn_mfma_f32_16x16x32_bf16(afr[1][ks], bfr, acc[1][ct], 0, 0, 0);
    }
  }

  // Non-temporal stores: out is never re-read; keep x + partials resident in L3
  // so the next kernels (and the next graph replay) hit L3 instead of HBM.
  float* ob = out + (size_t)b * NC * NN + n0;
#pragma unroll
  for (int rt = 0; rt < 2; ++rt)
#pragma unroll
    for (int ct = 0; ct < 8; ++ct)
#pragma unroll
      for (int r = 0; r < 4; ++r) {
        int o = wv * 32 + rt * 16 + q * 4 + r;
        int n = ct * 16 + l15;
        __builtin_nontemporal_store(acc[rt][ct][r], ob + (size_t)o * NN + n);
      }
}

extern "C" void kernel_launch(void* const* d_in, const int* in_sizes, int n_in,
                              void* d_out, int out_size, void* d_ws, size_t ws_size,
                              hipStream_t stream) {
  const float* x = (const float*)d_in[0];
  const float* w = (const float*)d_in[1];
  float* out = (float*)d_out;

  // adapt K-chunk count to available workspace (deterministic: depends only on ws_size)
  int chunks = 32;
  while (chunks > 1 &&
         (size_t)NB * chunks * NC * NC * sizeof(float) +           // partials
         (size_t)NB * NC * NC * sizeof(float) +                    // gram
         (size_t)NB * NC * NC * 2 > ws_size)                       // Mbf
    chunks >>= 1;
  int ksteps = (NN / chunks) / 64;

  char* wsp = (char*)d_ws;
  float* partials = (float*)wsp;
  wsp += (size_t)NB * chunks * NC * NC * sizeof(float);
  float* gram = (float*)wsp;
  wsp += (size_t)NB * NC * NC * sizeof(float);
  unsigned short* Mbf = (unsigned short*)wsp;

  hipLaunchKernelGGL(nlm_gram_kernel, dim3(NB * chunks), dim3(256), 0, stream,
                     x, partials, chunks, ksteps);
  hipLaunchKernelGGL(nlm_reduce_kernel, dim3(NB * 16), dim3(256), 0, stream,
                     partials, gram, chunks);
  hipLaunchKernelGGL(nlm_wgram_kernel, dim3(NB * 4), dim3(256), 0, stream,
                     gram, w, Mbf);
  hipLaunchKernelGGL(nlm_out_kernel, dim3(NB * 128), dim3(256), 0, stream,
                     x, Mbf, out);
}

// Round 3
// 88.282 us; speedup vs baseline: 1.1242x; 1.1242x over previous
//
#include <hip/hip_runtime.h>

typedef __attribute__((ext_vector_type(8))) short bf16x8;
typedef __attribute__((ext_vector_type(4))) float f32x4;
typedef __attribute__((ext_vector_type(4))) float f4v;

#define NB 16
#define NC 128
#define NN 16384

// RNE pack of two fp32 -> one u32 holding two bf16 (lo | hi<<16)
__device__ __forceinline__ unsigned int f2bf_pack(float lo, float hi) {
  unsigned int ulo = __float_as_uint(lo);
  unsigned int uhi = __float_as_uint(hi);
  ulo = (ulo + 0x7FFFu + ((ulo >> 16) & 1u)) >> 16;
  uhi = (uhi + 0x7FFFu + ((uhi >> 16) & 1u)) & 0xFFFF0000u;
  return ulo | uhi;
}

// ---------------- Kernel A: partial Gram per (batch, K-chunk) ----------------
// 2-step-deep register prefetch (pfA/pfB ping-pong, compile-time indices).
__global__ __launch_bounds__(256, 2)
void nlm_gram_kernel(const float* __restrict__ x, float* __restrict__ partials,
                     int chunks, int ksteps) {
  __shared__ __align__(16) char lds[2 * 128 * 64 * 2];  // 2 x [128 rows][64 k] bf16, swizzled
  const int t = threadIdx.x;
  const int b  = blockIdx.x / chunks;
  const int ch = blockIdx.x % chunks;
  const int lane = t & 63, wv = t >> 6, l15 = lane & 15, q = lane >> 4;
  const int kc = ksteps * 64;

  const float* xb = x + (size_t)b * NC * NN + (size_t)ch * kc;

  f32x4 acc[2][8];
#pragma unroll
  for (int i = 0; i < 2; ++i)
#pragma unroll
    for (int j = 0; j < 8; ++j) acc[i][j] = (f32x4){0.f, 0.f, 0.f, 0.f};

  // staging tasks: 128 rows x 8 segs(8 floats) = 1024 tasks / 256 thr = 4 each
  int srow[4], sseg[4];
#pragma unroll
  for (int i = 0; i < 4; ++i) { int id = t + 256 * i; srow[i] = id >> 3; sseg[i] = id & 7; }

  f4v pfA[4][2], pfB[4][2];

#define LOADPF(PF, KS)                                                      \
  {                                                                         \
    _Pragma("unroll") for (int i = 0; i < 4; ++i) {                         \
      const float* src = xb + (size_t)srow[i] * NN + (KS)*64 + sseg[i] * 8; \
      PF[i][0] = *(const f4v*)src;                                          \
      PF[i][1] = *(const f4v*)(src + 4);                                    \
    }                                                                       \
  }

#define PACKPF(PF, BUF)                                                     \
  {                                                                         \
    _Pragma("unroll") for (int i = 0; i < 4; ++i) {                         \
      uint4 pk;                                                             \
      pk.x = f2bf_pack(PF[i][0][0], PF[i][0][1]);                           \
      pk.y = f2bf_pack(PF[i][0][2], PF[i][0][3]);                           \
      pk.z = f2bf_pack(PF[i][1][0], PF[i][1][1]);                           \
      pk.w = f2bf_pack(PF[i][1][2], PF[i][1][3]);                           \
      int byte = (srow[i] * 128 + sseg[i] * 16) ^ ((srow[i] & 7) << 4);     \
      *(uint4*)((BUF) + byte) = pk;                                         \
    }                                                                       \
  }

#define MFMAPH(BUF)                                                                          \
  {                                                                                          \
    _Pragma("unroll") for (int kh = 0; kh < 2; ++kh) {                                       \
      const int kbyte = kh * 64 + q * 16;                                                    \
      int ra = wv * 32 + l15;                                                                \
      bf16x8 a0 = *(const bf16x8*)((BUF) + ((ra * 128 + kbyte) ^ ((ra & 7) << 4)));          \
      int rb = wv * 32 + 16 + l15;                                                           \
      bf16x8 a1 = *(const bf16x8*)((BUF) + ((rb * 128 + kbyte) ^ ((rb & 7) << 4)));          \
      _Pragma("unroll") for (int ct = 0; ct < 8; ++ct) {                                     \
        int rc = ct * 16 + l15;                                                              \
        bf16x8 bb = *(const bf16x8*)((BUF) + ((rc * 128 + kbyte) ^ ((rc & 7) << 4)));        \
        acc[0][ct] = __builtin_amdgcn_mfma_f32_16x16x32_bf16(a0, bb, acc[0][ct], 0, 0, 0);   \
        acc[1][ct] = __builtin_amdgcn_mfma_f32_16x16x32_bf16(a1, bb, acc[1][ct], 0, 0, 0);   \
      }                                                                                      \
    }                                                                                        \
  }

  char* buf0 = lds;
  char* buf1 = lds + 16384;

  // prologue: step0 -> pfA -> buf0; issue step1 -> pfB
  LOADPF(pfA, 0);
  PACKPF(pfA, buf0);
  if (1 < ksteps) LOADPF(pfB, 1);
  __syncthreads();

  for (int ks = 0; ks < ksteps; ks += 2) {
    // even step: compute buf0 (step ks); pfB holds ks+1
    if (ks + 2 < ksteps) LOADPF(pfA, ks + 2);
    MFMAPH(buf0);
    if (ks + 1 < ksteps) PACKPF(pfB, buf1);
    __syncthreads();
    // odd step: compute buf1 (step ks+1); pfA holds ks+2
    if (ks + 1 < ksteps) {
      if (ks + 3 < ksteps) LOADPF(pfB, ks + 3);
      MFMAPH(buf1);
      if (ks + 2 < ksteps) PACKPF(pfA, buf0);
      __syncthreads();
    }
  }

  // C/D layout (verified m89): col = lane&15, row = (lane>>4)*4 + reg
  float* part = partials + (size_t)blockIdx.x * (NC * NC);
#pragma unroll
  for (int rt = 0; rt < 2; ++rt)
#pragma unroll
    for (int ct = 0; ct < 8; ++ct)
#pragma unroll
      for (int r = 0; r < 4; ++r) {
        int i = wv * 32 + rt * 16 + q * 4 + r;
        int j = ct * 16 + l15;
        part[i * 128 + j] = acc[rt][ct][r];
      }
#undef LOADPF
#undef PACKPF
#undef MFMAPH
}

// ---------------- Kernel B: fused reduce + M = w @ gram (via gram symmetry) ----------------
// gram is exactly symmetric, so M[o,d] = dot(w[o,:], gram[d,:]).
// Block (b, d-slice of 8 gram ROWS): coalesced reduce of 8 rows -> 4 KiB LDS,
// then 256 threads compute the 8x128 M-column slice.
__global__ __launch_bounds__(256)
void nlm_gramw_kernel(const float* __restrict__ partials, const float* __restrict__ w,
                      unsigned short* __restrict__ Mbf, int chunks) {
  __shared__ __align__(16) float glds[8 * 128];
  const int t = threadIdx.x;
  const int b  = blockIdx.x >> 4;
  const int d0 = (blockIdx.x & 15) * 8;

  // reduce gram rows d0..d0+7 over all chunk-partials (fully coalesced: 4 KiB runs)
  const int rr = t >> 5;          // 0..7
  const int c4 = (t & 31) * 4;    // 0..124
  const float* pb = partials + (size_t)b * chunks * (NC * NC) + (d0 + rr) * 128 + c4;
  f4v s = (f4v){0.f, 0.f, 0.f, 0.f};
  for (int chn = 0; chn < chunks; ++chn)
    s += *(const f4v*)(pb + (size_t)chn * (NC * NC));
  s *= (1.0f / 16384.0f);
  *(f4v*)(glds + rr * 128 + c4) = s;
  __syncthreads();

  // M[o, d0+j0..+3] = dot(w[o,:], gram[d0+j0+j,:])
  const int o  = t & 127;
  const int j0 = (t >> 7) * 4;  // 0 or 4
  float m[4] = {0.f, 0.f, 0.f, 0.f};
  for (int c = 0; c < 128; c += 4) {
    f4v wv = *(const f4v*)(w + o * 128 + c);
#pragma unroll
    for (int j = 0; j < 4; ++j) {
      f4v gv = *(const f4v*)(glds + (j0 + j) * 128 + c);  // broadcast across lanes
      m[j] = fmaf(wv[0], gv[0], m[j]);
      m[j] = fmaf(wv[1], gv[1], m[j]);
      m[j] = fmaf(wv[2], gv[2], m[j]);
      m[j] = fmaf(wv[3], gv[3], m[j]);
    }
  }
  uint2 pk;
  pk.x = f2bf_pack(m[0], m[1]);
  pk.y = f2bf_pack(m[2], m[3]);
  *(uint2*)(Mbf + (size_t)b * NC * NC + o * 128 + d0 + j0) = pk;
}

// ---------------- Kernel C: out = M @ X  (128 x 128 output tile per block) ----------------
__global__ __launch_bounds__(256, 2)
void nlm_out_kernel(const float* __restrict__ x, const unsigned short* __restrict__ Mbf,
                    float* __restrict__ out) {
  __shared__ __align__(16) char lds[128 * 128 * 2];  // X^T tile: [n=128][c=128] bf16, swizzled
  const int t = threadIdx.x;
  const int b = blockIdx.x >> 7;
  const int n0 = (blockIdx.x & 127) * 128;
  const int lane = t & 63, wv = t >> 6, l15 = lane & 15, q = lane >> 4;

  // A-operand (M) fragments straight from global into registers; L2-resident.
  bf16x8 afr[2][4];
  const unsigned short* mb = Mbf + (size_t)b * NC * NC;
#pragma unroll
  for (int rt = 0; rt < 2; ++rt)
#pragma unroll
    for (int ks = 0; ks < 4; ++ks) {
      int o = wv * 32 + rt * 16 + l15;
      afr[rt][ks] = *(const bf16x8*)(mb + o * 128 + ks * 32 + q * 8);
    }

  // stage X[b, :, n0:n0+128] transposed into LDS (8c x 4n register transpose per task)
  const float* xb = x + (size_t)b * NC * NN + n0;
#pragma unroll
  for (int i = 0; i < 2; ++i) {
    int id = t + 256 * i;
    int nb = id & 31, cb = id >> 5;  // cb in 0..15 (8 c-rows each)
    const float* src = xb + (size_t)(cb * 8) * NN + nb * 4;
    f4v v[8];
#pragma unroll
    for (int r = 0; r < 8; ++r) v[r] = *(const f4v*)(src + (size_t)r * NN);
#pragma unroll
    for (int j = 0; j < 4; ++j) {
      int n = nb * 4 + j;
      uint4 pk;
      pk.x = f2bf_pack(v[0][j], v[1][j]);
      pk.y = f2bf_pack(v[2][j], v[3][j]);
      pk.z = f2bf_pack(v[4][j], v[5][j]);
      pk.w = f2bf_pack(v[6][j], v[7][j]);
      int byte = (n * 256 + cb * 16) ^ ((((n & 7) ^ ((n >> 3) & 7))) << 4);
      *(uint4*)(lds + byte) = pk;
    }
  }
  __syncthreads();

  f32x4 acc[2][8];
#pragma unroll
  for (int i = 0; i < 2; ++i)
#pragma unroll
    for (int j = 0; j < 8; ++j) acc[i][j] = (f32x4){0.f, 0.f, 0.f, 0.f};

#pragma unroll
  for (int ks = 0; ks < 4; ++ks) {
#pragma unroll
    for (int ct = 0; ct < 8; ++ct) {
      int n = ct * 16 + l15;
      int byte = (n * 256 + ks * 64 + q * 16) ^ ((((n & 7) ^ ((n >> 3) & 7))) << 4);
      bf16x8 bfr = *(const bf16x8*)(lds + byte);
      acc[0][ct] = __builtin_amdgcn_mfma_f32_16x16x32_bf16(afr[0][ks], bfr, acc[0][ct], 0, 0, 0);
      acc[1][ct] = __builtin_amdgcn_mfma_f32_16x16x32_bf16(afr[1][ks], bfr, acc[1][ct], 0, 0, 0);
    }
  }

  float* ob = out + (size_t)b * NC * NN + n0;
#pragma unroll
  for (int rt = 0; rt < 2; ++rt)
#pragma unroll
    for (int ct = 0; ct < 8; ++ct)
#pragma unroll
      for (int r = 0; r < 4; ++r) {
        int o = wv * 32 + rt * 16 + q * 4 + r;
        int n = ct * 16 + l15;
        ob[(size_t)o * NN + n] = acc[rt][ct][r];
      }
}

extern "C" void kernel_launch(void* const* d_in, const int* in_sizes, int n_in,
                              void* d_out, int out_size, void* d_ws, size_t ws_size,
                              hipStream_t stream) {
  const float* x = (const float*)d_in[0];
  const float* w = (const float*)d_in[1];
  float* out = (float*)d_out;

  // adapt K-chunk count to available workspace (deterministic: depends only on ws_size)
  int chunks = 32;
  while (chunks > 1 &&
         (size_t)NB * chunks * NC * NC * sizeof(float) +  // partials
         (size_t)NB * NC * NC * 2 > ws_size)              // Mbf
    chunks >>= 1;
  int ksteps = (NN / chunks) / 64;

  char* wsp = (char*)d_ws;
  float* partials = (float*)wsp;
  wsp += (size_t)NB * chunks * NC * NC * sizeof(float);
  unsigned short* Mbf = (unsigned short*)wsp;

  hipLaunchKernelGGL(nlm_gram_kernel, dim3(NB * chunks), dim3(256), 0, stream,
                     x, partials, chunks, ksteps);
  hipLaunchKernelGGL(nlm_gramw_kernel, dim3(NB * 16), dim3(256), 0, stream,
                     partials, w, Mbf, chunks);
  hipLaunchKernelGGL(nlm_out_kernel, dim3(NB * 128), dim3(256), 0, stream,
                     x, Mbf, out);
}

// Round 4
// 88.259 us; speedup vs baseline: 1.1245x; 1.0003x over previous
//
#include <hip/hip_runtime.h>

typedef __attribute__((ext_vector_type(8))) short bf16x8;
typedef __attribute__((ext_vector_type(4))) float f32x4;
typedef __attribute__((ext_vector_type(4))) float f4v;
typedef __attribute__((ext_vector_type(4))) unsigned short u16x4;

#define NB 16
#define NC 128
#define NN 16384

// RNE pack of two fp32 -> one u32 holding two bf16 (lo | hi<<16)
__device__ __forceinline__ unsigned int f2bf_pack(float lo, float hi) {
  unsigned int ulo = __float_as_uint(lo);
  unsigned int uhi = __float_as_uint(hi);
  ulo = (ulo + 0x7FFFu + ((ulo >> 16) & 1u)) >> 16;
  uhi = (uhi + 0x7FFFu + ((uhi >> 16) & 1u)) & 0xFFFF0000u;
  return ulo | uhi;
}

__device__ __forceinline__ unsigned short f2bf_one(float v) {
  unsigned int u = __float_as_uint(v);
  return (unsigned short)((u + 0x7FFFu + ((u >> 16) & 1u)) >> 16);
}

__device__ __forceinline__ float bf2f(unsigned short u) {
  return __uint_as_float(((unsigned int)u) << 16);
}

// ---------------- Kernel A: partial Gram per (batch, K-chunk) ----------------
// 2-step-deep register prefetch (pfA/pfB ping-pong, compile-time indices).
// Partials stored as bf16 (halves the round-trip traffic; error ~8e-4 on out).
__global__ __launch_bounds__(256, 2)
void nlm_gram_kernel(const float* __restrict__ x, unsigned short* __restrict__ partials,
                     int chunks, int ksteps) {
  __shared__ __align__(16) char lds[2 * 128 * 64 * 2];  // 2 x [128 rows][64 k] bf16, swizzled
  const int t = threadIdx.x;
  const int b  = blockIdx.x / chunks;
  const int ch = blockIdx.x % chunks;
  const int lane = t & 63, wv = t >> 6, l15 = lane & 15, q = lane >> 4;
  const int kc = ksteps * 64;

  const float* xb = x + (size_t)b * NC * NN + (size_t)ch * kc;

  f32x4 acc[2][8];
#pragma unroll
  for (int i = 0; i < 2; ++i)
#pragma unroll
    for (int j = 0; j < 8; ++j) acc[i][j] = (f32x4){0.f, 0.f, 0.f, 0.f};

  // staging tasks: 128 rows x 8 segs(8 floats) = 1024 tasks / 256 thr = 4 each
  int srow[4], sseg[4];
#pragma unroll
  for (int i = 0; i < 4; ++i) { int id = t + 256 * i; srow[i] = id >> 3; sseg[i] = id & 7; }

  f4v pfA[4][2], pfB[4][2];

#define LOADPF(PF, KS)                                                      \
  {                                                                         \
    _Pragma("unroll") for (int i = 0; i < 4; ++i) {                         \
      const float* src = xb + (size_t)srow[i] * NN + (KS)*64 + sseg[i] * 8; \
      PF[i][0] = *(const f4v*)src;                                          \
      PF[i][1] = *(const f4v*)(src + 4);                                    \
    }                                                                       \
  }

#define PACKPF(PF, BUF)                                                     \
  {                                                                         \
    _Pragma("unroll") for (int i = 0; i < 4; ++i) {                         \
      uint4 pk;                                                             \
      pk.x = f2bf_pack(PF[i][0][0], PF[i][0][1]);                           \
      pk.y = f2bf_pack(PF[i][0][2], PF[i][0][3]);                           \
      pk.z = f2bf_pack(PF[i][1][0], PF[i][1][1]);                           \
      pk.w = f2bf_pack(PF[i][1][2], PF[i][1][3]);                           \
      int byte = (srow[i] * 128 + sseg[i] * 16) ^ ((srow[i] & 7) << 4);     \
      *(uint4*)((BUF) + byte) = pk;                                         \
    }                                                                       \
  }

#define MFMAPH(BUF)                                                                          \
  {                                                                                          \
    _Pragma("unroll") for (int kh = 0; kh < 2; ++kh) {                                       \
      const int kbyte = kh * 64 + q * 16;                                                    \
      int ra = wv * 32 + l15;                                                                \
      bf16x8 a0 = *(const bf16x8*)((BUF) + ((ra * 128 + kbyte) ^ ((ra & 7) << 4)));          \
      int rb = wv * 32 + 16 + l15;                                                           \
      bf16x8 a1 = *(const bf16x8*)((BUF) + ((rb * 128 + kbyte) ^ ((rb & 7) << 4)));          \
      _Pragma("unroll") for (int ct = 0; ct < 8; ++ct) {                                     \
        int rc = ct * 16 + l15;                                                              \
        bf16x8 bb = *(const bf16x8*)((BUF) + ((rc * 128 + kbyte) ^ ((rc & 7) << 4)));        \
        acc[0][ct] = __builtin_amdgcn_mfma_f32_16x16x32_bf16(a0, bb, acc[0][ct], 0, 0, 0);   \
        acc[1][ct] = __builtin_amdgcn_mfma_f32_16x16x32_bf16(a1, bb, acc[1][ct], 0, 0, 0);   \
      }                                                                                      \
    }                                                                                        \
  }

  char* buf0 = lds;
  char* buf1 = lds + 16384;

  // prologue: step0 -> pfA -> buf0; issue step1 -> pfB
  LOADPF(pfA, 0);
  PACKPF(pfA, buf0);
  if (1 < ksteps) LOADPF(pfB, 1);
  __syncthreads();

  for (int ks = 0; ks < ksteps; ks += 2) {
    // even step: compute buf0 (step ks); pfB holds ks+1
    if (ks + 2 < ksteps) LOADPF(pfA, ks + 2);
    MFMAPH(buf0);
    if (ks + 1 < ksteps) PACKPF(pfB, buf1);
    __syncthreads();
    // odd step: compute buf1 (step ks+1); pfA holds ks+2
    if (ks + 1 < ksteps) {
      if (ks + 3 < ksteps) LOADPF(pfB, ks + 3);
      MFMAPH(buf1);
      if (ks + 2 < ksteps) PACKPF(pfA, buf0);
      __syncthreads();
    }
  }

  // C/D layout (verified m89): col = lane&15, row = (lane>>4)*4 + reg
  unsigned short* part = partials + (size_t)blockIdx.x * (NC * NC);
#pragma unroll
  for (int rt = 0; rt < 2; ++rt)
#pragma unroll
    for (int ct = 0; ct < 8; ++ct)
#pragma unroll
      for (int r = 0; r < 4; ++r) {
        int i = wv * 32 + rt * 16 + q * 4 + r;
        int j = ct * 16 + l15;
        part[i * 128 + j] = f2bf_one(acc[rt][ct][r]);
      }
#undef LOADPF
#undef PACKPF
#undef MFMAPH
}

// ---------------- Kernel B: fused reduce + M = w @ gram (via gram symmetry) ----------------
// gram is exactly symmetric, so M[o,d] = dot(w[o,:], gram[d,:]).
// Block (b, d-slice of 8 gram ROWS): coalesced bf16 reduce of 8 rows -> 4 KiB LDS,
// then 256 threads compute the 8x128 M-column slice.
__global__ __launch_bounds__(256)
void nlm_gramw_kernel(const unsigned short* __restrict__ partials, const float* __restrict__ w,
                      unsigned short* __restrict__ Mbf, int chunks) {
  __shared__ __align__(16) float glds[8 * 128];
  const int t = threadIdx.x;
  const int b  = blockIdx.x >> 4;
  const int d0 = (blockIdx.x & 15) * 8;

  // reduce gram rows d0..d0+7 over all chunk-partials (coalesced: 256-B runs)
  const int rr = t >> 5;          // 0..7
  const int c4 = (t & 31) * 4;    // 0..124
  const unsigned short* pb =
      partials + (size_t)b * chunks * (NC * NC) + (d0 + rr) * 128 + c4;
  f4v s = (f4v){0.f, 0.f, 0.f, 0.f};
  for (int chn = 0; chn < chunks; ++chn) {
    u16x4 v = *(const u16x4*)(pb + (size_t)chn * (NC * NC));
    s[0] += bf2f(v[0]);
    s[1] += bf2f(v[1]);
    s[2] += bf2f(v[2]);
    s[3] += bf2f(v[3]);
  }
  s *= (1.0f / 16384.0f);
  *(f4v*)(glds + rr * 128 + c4) = s;
  __syncthreads();

  // M[o, d0+j0..+3] = dot(w[o,:], gram[d0+j0+j,:])
  const int o  = t & 127;
  const int j0 = (t >> 7) * 4;  // 0 or 4
  float m[4] = {0.f, 0.f, 0.f, 0.f};
  for (int c = 0; c < 128; c += 4) {
    f4v wv = *(const f4v*)(w + o * 128 + c);
#pragma unroll
    for (int j = 0; j < 4; ++j) {
      f4v gv = *(const f4v*)(glds + (j0 + j) * 128 + c);  // broadcast across lanes
      m[j] = fmaf(wv[0], gv[0], m[j]);
      m[j] = fmaf(wv[1], gv[1], m[j]);
      m[j] = fmaf(wv[2], gv[2], m[j]);
      m[j] = fmaf(wv[3], gv[3], m[j]);
    }
  }
  uint2 pk;
  pk.x = f2bf_pack(m[0], m[1]);
  pk.y = f2bf_pack(m[2], m[3]);
  *(uint2*)(Mbf + (size_t)b * NC * NC + o * 128 + d0 + j0) = pk;
}

// ---------------- Kernel C: out = M @ X  (128 x 128 output tile per block) ----------------
__global__ __launch_bounds__(256, 2)
void nlm_out_kernel(const float* __restrict__ x, const unsigned short* __restrict__ Mbf,
                    float* __restrict__ out) {
  __shared__ __align__(16) char lds[128 * 128 * 2];  // X^T tile: [n=128][c=128] bf16, swizzled
  const int t = threadIdx.x;
  // Reverse batch order: A touched x[b=15] last, so consume LRU-warmest batches
  // first before our own out-writes build L3 eviction pressure.
  const int b = (NB - 1) - (blockIdx.x >> 7);
  const int n0 = (blockIdx.x & 127) * 128;
  const int lane = t & 63, wv = t >> 6, l15 = lane & 15, q = lane >> 4;

  // A-operand (M) fragments straight from global into registers; L2-resident.
  bf16x8 afr[2][4];
  const unsigned short* mb = Mbf + (size_t)b * NC * NC;
#pragma unroll
  for (int rt = 0; rt < 2; ++rt)
#pragma unroll
    for (int ks = 0; ks < 4; ++ks) {
      int o = wv * 32 + rt * 16 + l15;
      afr[rt][ks] = *(const bf16x8*)(mb + o * 128 + ks * 32 + q * 8);
    }

  // stage X[b, :, n0:n0+128] transposed into LDS (8c x 4n register transpose per task)
  const float* xb = x + (size_t)b * NC * NN + n0;
#pragma unroll
  for (int i = 0; i < 2; ++i) {
    int id = t + 256 * i;
    int nb = id & 31, cb = id >> 5;  // cb in 0..15 (8 c-rows each)
    const float* src = xb + (size_t)(cb * 8) * NN + nb * 4;
    f4v v[8];
#pragma unroll
    for (int r = 0; r < 8; ++r) v[r] = *(const f4v*)(src + (size_t)r * NN);
#pragma unroll
    for (int j = 0; j < 4; ++j) {
      int n = nb * 4 + j;
      uint4 pk;
      pk.x = f2bf_pack(v[0][j], v[1][j]);
      pk.y = f2bf_pack(v[2][j], v[3][j]);
      pk.z = f2bf_pack(v[4][j], v[5][j]);
      pk.w = f2bf_pack(v[6][j], v[7][j]);
      int byte = (n * 256 + cb * 16) ^ ((((n & 7) ^ ((n >> 3) & 7))) << 4);
      *(uint4*)(lds + byte) = pk;
    }
  }
  __syncthreads();

  f32x4 acc[2][8];
#pragma unroll
  for (int i = 0; i < 2; ++i)
#pragma unroll
    for (int j = 0; j < 8; ++j) acc[i][j] = (f32x4){0.f, 0.f, 0.f, 0.f};

#pragma unroll
  for (int ks = 0; ks < 4; ++ks) {
#pragma unroll
    for (int ct = 0; ct < 8; ++ct) {
      int n = ct * 16 + l15;
      int byte = (n * 256 + ks * 64 + q * 16) ^ ((((n & 7) ^ ((n >> 3) & 7))) << 4);
      bf16x8 bfr = *(const bf16x8*)(lds + byte);
      acc[0][ct] = __builtin_amdgcn_mfma_f32_16x16x32_bf16(afr[0][ks], bfr, acc[0][ct], 0, 0, 0);
      acc[1][ct] = __builtin_amdgcn_mfma_f32_16x16x32_bf16(afr[1][ks], bfr, acc[1][ct], 0, 0, 0);
    }
  }

  float* ob = out + (size_t)b * NC * NN + n0;
#pragma unroll
  for (int rt = 0; rt < 2; ++rt)
#pragma unroll
    for (int ct = 0; ct < 8; ++ct)
#pragma unroll
      for (int r = 0; r < 4; ++r) {
        int o = wv * 32 + rt * 16 + q * 4 + r;
        int n = ct * 16 + l15;
        ob[(size_t)o * NN + n] = acc[rt][ct][r];
      }
}

extern "C" void kernel_launch(void* const* d_in, const int* in_sizes, int n_in,
                              void* d_out, int out_size, void* d_ws, size_t ws_size,
                              hipStream_t stream) {
  const float* x = (const float*)d_in[0];
  const float* w = (const float*)d_in[1];
  float* out = (float*)d_out;

  // adapt K-chunk count to available workspace (deterministic: depends only on ws_size)
  int chunks = 32;
  while (chunks > 1 &&
         (size_t)NB * chunks * NC * NC * 2 +   // partials (bf16)
         (size_t)NB * NC * NC * 2 > ws_size)   // Mbf
    chunks >>= 1;
  int ksteps = (NN / chunks) / 64;

  char* wsp = (char*)d_ws;
  unsigned short* partials = (unsigned short*)wsp;
  wsp += (size_t)NB * chunks * NC * NC * 2;
  unsigned short* Mbf = (unsigned short*)wsp;

  hipLaunchKernelGGL(nlm_gram_kernel, dim3(NB * chunks), dim3(256), 0, stream,
                     x, partials, chunks, ksteps);
  hipLaunchKernelGGL(nlm_gramw_kernel, dim3(NB * 16), dim3(256), 0, stream,
                     partials, w, Mbf, chunks);
  hipLaunchKernelGGL(nlm_out_kernel, dim3(NB * 128), dim3(256), 0, stream,
                     x, Mbf, out);
}